// Round 2
// baseline (14838.979 us; speedup 1.0000x reference)
//
#include <hip/hip_runtime.h>
#include <cstdint>
#include <cstddef>

typedef _Float16 f16;
typedef _Float16 f16x4 __attribute__((ext_vector_type(4)));
typedef _Float16 f16x8 __attribute__((ext_vector_type(8)));
typedef float f32x4 __attribute__((ext_vector_type(4)));

#define MFMA16(a, b, c) __builtin_amdgcn_mfma_f32_16x16x16f16((a), (b), (c), 0, 0, 0)

constexpr int TT = 1024, DIN = 128, DH = 512, DOUT = 128;
constexpr size_t O_ELEMS = (size_t)64 * 1024 * 128;

// Conflict-free swizzle for [row][1KB] tiles: row bits 2-3 -> byte bits 5-6,
// row bits 0-1 -> byte bits 7-8. Verified: b64 frag reads = 4 words/bank (floor),
// b16 epilogue reads/writes = 32 banks, 2 lanes per dword.
__device__ __forceinline__ uint32_t srow(uint32_t r) {
    return ((r & 12u) << 3) | ((r & 3u) << 7);
}

// ---------------- Pass 1: xI = X(65536x128) @ wI(128x512) -> H region (fp32) ----------------
__global__ __launch_bounds__(256, 1) void k_xI(const float* __restrict__ X,
                                               const float* __restrict__ wI,
                                               float* __restrict__ xI) {
    __shared__ __align__(16) f16 Bt[DH][136];  // wI^T [n][k], padded stride
    __shared__ __align__(16) f16 At[64][136];  // X tile [m][k], padded stride
    const int tid = threadIdx.x;
    const int wv = tid >> 6, ln = tid & 63, l15 = ln & 15, g = ln >> 4;
    const int m0 = (int)blockIdx.x * 64;

    for (int u = 0; u < 64; ++u) {
        int flat = u * 256 + tid;
        int r = flat >> 7;
        int c4 = (flat & 127) << 2;
        const float4 w4 = *(const float4*)(wI + (size_t)r * DH + c4);
        Bt[c4 + 0][r] = (f16)w4.x;
        Bt[c4 + 1][r] = (f16)w4.y;
        Bt[c4 + 2][r] = (f16)w4.z;
        Bt[c4 + 3][r] = (f16)w4.w;
    }
    {
        int r = tid >> 2;
        int cb = (tid & 3) << 5;
        #pragma unroll
        for (int u = 0; u < 8; ++u) {
            int c = cb + u * 4;
            const float4 x4 = *(const float4*)(X + (size_t)(m0 + r) * DIN + c);
            f16x4 h4;
            h4[0] = (f16)x4.x; h4[1] = (f16)x4.y; h4[2] = (f16)x4.z; h4[3] = (f16)x4.w;
            *(f16x4*)((char*)&At[r][0] + c * 2) = h4;
        }
    }
    __syncthreads();

    f32x4 acc[4][8];
    #pragma unroll
    for (int mt = 0; mt < 4; ++mt)
        #pragma unroll
        for (int nt = 0; nt < 8; ++nt) acc[mt][nt] = (f32x4){0.f, 0.f, 0.f, 0.f};

    #pragma unroll
    for (int c = 0; c < 8; ++c) {
        const int k0 = c * 16 + g * 4;
        f16x4 a[4];
        #pragma unroll
        for (int mt = 0; mt < 4; ++mt)
            a[mt] = *(const f16x4*)((const char*)&At[mt * 16 + l15][0] + k0 * 2);
        #pragma unroll
        for (int nt = 0; nt < 8; ++nt) {
            const int n = wv * 128 + nt * 16 + l15;
            const f16x4 b = *(const f16x4*)((const char*)&Bt[n][0] + k0 * 2);
            #pragma unroll
            for (int mt = 0; mt < 4; ++mt) acc[mt][nt] = MFMA16(a[mt], b, acc[mt][nt]);
        }
    }
    #pragma unroll
    for (int mt = 0; mt < 4; ++mt) {
        #pragma unroll
        for (int i = 0; i < 4; ++i) {
            const int m = m0 + mt * 16 + g * 4 + i;
            float* orow = xI + (size_t)m * DH + wv * 128 + l15;
            #pragma unroll
            for (int nt = 0; nt < 8; ++nt) orow[nt * 16] = acc[mt][nt][i];
        }
    }
}

// ---------------- Pass 2: recurrent scan (4 blocks, 16 batches each, in place on H) ------------
// LDS map (single char array => guaranteed offsets):
//   [0, 16K)      hb : h state, f16 [16 rows][512], swizzled
//   [16K, 32K)    xs : xI(t) staging, f16 [16 rows][512], swizzled
//   [32K, 160K)   Bl : 8 weight j-tiles (2/wave), [16 j][512 k] f16, swizzled
__global__ __launch_bounds__(256, 1) void k_scan(const float* __restrict__ wR,
                                                 const float* __restrict__ h0,
                                                 float* __restrict__ Hb) {
    __shared__ __align__(16) char sm[163840];
    const int tid = threadIdx.x;
    const int wv = tid >> 6, ln = tid & 63, l15 = ln & 15, g = ln >> 4;
    const int bb = (int)blockIdx.x * 16;

    // ---- stage wR: 6 register j-tiles per wave ----
    f16x4 Brf[6][32];
    #pragma unroll
    for (int q = 0; q < 6; ++q) {
        const int j = wv * 128 + q * 16 + l15;
        #pragma unroll
        for (int c = 0; c < 32; ++c) {
            const int k = c * 16 + g * 4;
            const float* p = wR + (size_t)k * DH + j;
            f16x4 v;
            v[0] = (f16)p[0];
            v[1] = (f16)p[DH];
            v[2] = (f16)p[2 * DH];
            v[3] = (f16)p[3 * DH];
            Brf[q][c] = v;
        }
    }
    // ---- stage wR: 2 LDS j-tiles per wave (j = wv*128 + 96 .. +127) ----
    {
        char* base = sm + 32768 + (size_t)wv * 32768;
        for (int idx = ln; idx < 32 * 512; idx += 64) {
            const uint32_t jj = (uint32_t)(idx & 31);
            const uint32_t k = (uint32_t)(idx >> 5);
            const float v = wR[(size_t)k * DH + wv * 128 + 96 + jj];
            const uint32_t row = jj & 15u, tile = jj >> 4;
            *(f16*)(base + tile * 16384 + row * 1024 + ((k * 2) ^ srow(row))) = (f16)v;
        }
    }
    // ---- h0 broadcast into hb ----
    for (int j = tid; j < DH; j += 256) {
        const f16 v = (f16)h0[j];
        #pragma unroll
        for (uint32_t r = 0; r < 16; ++r)
            *(f16*)(sm + r * 1024 + (((uint32_t)(2 * j)) ^ srow(r))) = v;
    }

    // xI loader: thread covers row tid>>4, 32 consecutive floats at col (tid&15)*32
    const float* xp = Hb + (size_t)(bb + (tid >> 4)) * TT * DH + (tid & 15) * 32;
    const int jbase = wv * 128 + l15;
    float* Hst[4];
    #pragma unroll
    for (int i = 0; i < 4; ++i)
        Hst[i] = Hb + (size_t)(bb + g * 4 + i) * TT * DH + jbase;

    const uint32_t swA = srow((uint32_t)l15);
    const char* hb_l = sm + (uint32_t)l15 * 1024 + (uint32_t)g * 8;
    const char* bl_l = sm + 32768 + (uint32_t)wv * 32768 + (uint32_t)l15 * 1024 + (uint32_t)g * 8;
    uint32_t rowoff[4];
    #pragma unroll
    for (uint32_t i = 0; i < 4; ++i) {
        const uint32_t r = (uint32_t)g * 4 + i;
        rowoff[i] = r * 1024 + srow(r);
    }
    const uint32_t jb2 = (uint32_t)jbase * 2;

    // prologue: fetch xI(0) into registers
    float4 xr[8];
    #pragma unroll
    for (int u = 0; u < 8; ++u) xr[u] = *(const float4*)(xp + u * 4);

    f32x4 acc[8];
    #pragma unroll
    for (int q = 0; q < 8; ++q) acc[q] = (f32x4){0.f, 0.f, 0.f, 0.f};

    __syncthreads();

    #pragma unroll 1
    for (int t = 0; t < TT; ++t) {
        // xs(t) <- xr (f16, swizzled, b128 writes). Safe: after barrier2(t-1).
        {
            char* xw = sm + 16384 + (uint32_t)(tid >> 4) * 1024;
            const uint32_t sr = srow((uint32_t)(tid >> 4));
            #pragma unroll
            for (int u = 0; u < 4; ++u) {
                const float4 a0 = xr[u * 2], a1 = xr[u * 2 + 1];
                f16x8 h;
                h[0] = (f16)a0.x; h[1] = (f16)a0.y; h[2] = (f16)a0.z; h[3] = (f16)a0.w;
                h[4] = (f16)a1.x; h[5] = (f16)a1.y; h[6] = (f16)a1.z; h[7] = (f16)a1.w;
                *(f16x8*)(xw + ((((uint32_t)(tid & 15)) * 64 + (uint32_t)u * 16) ^ sr)) = h;
            }
        }
        // deferred H stores for step t-1 (Hst points at row t)
        if (t > 0) {
            #pragma unroll
            for (int q = 0; q < 8; ++q)
                #pragma unroll
                for (int i = 0; i < 4; ++i)
                    Hst[i][-512 + q * 16] = acc[q][i];
        }
        // issue xI(t+1) loads; latency hides under the MFMA phase
        if (t < TT - 1) {
            #pragma unroll
            for (int u = 0; u < 8; ++u) xr[u] = *(const float4*)(xp + DH + u * 4);
        }
        #pragma unroll
        for (int q = 0; q < 8; ++q) acc[q] = (f32x4){0.f, 0.f, 0.f, 0.f};

        // h @ wR : 32 k-chunks x (6 reg + 2 LDS) j-tiles
        #pragma unroll
        for (int c = 0; c < 32; ++c) {
            const uint32_t cx = ((uint32_t)(c * 32)) ^ swA;
            const f16x4 a = *(const f16x4*)(hb_l + cx);
            #pragma unroll
            for (int q = 0; q < 6; ++q) acc[q] = MFMA16(a, Brf[q][c], acc[q]);
            const f16x4 b6 = *(const f16x4*)(bl_l + cx);
            acc[6] = MFMA16(a, b6, acc[6]);
            const f16x4 b7 = *(const f16x4*)(bl_l + cx + 16384);
            acc[7] = MFMA16(a, b7, acc[7]);
        }
        __syncthreads();  // hb reads done; xs(t) writes visible

        // epilogue: th = tanh(acc + xI(t)); acc keeps fp32 th; hb <- f16 th
        #pragma unroll
        for (int q = 0; q < 8; ++q) {
            const uint32_t jq2 = jb2 + (uint32_t)q * 32;
            #pragma unroll
            for (int i = 0; i < 4; ++i) {
                const uint32_t off = rowoff[i] ^ jq2;
                const float xv = (float)*(const f16*)(sm + 16384 + off);
                const float x = acc[q][i] + xv;
                const float e = __builtin_amdgcn_exp2f(x * 2.8853900817779268f);
                const float th = 1.0f - 2.0f * __builtin_amdgcn_rcpf(e + 1.0f);
                acc[q][i] = th;
                *(f16*)(sm + off) = (f16)th;  // hb(t+1)
            }
        }
        __syncthreads();  // hb(t+1) ready for next MFMA phase

        xp += DH;
        #pragma unroll
        for (int i = 0; i < 4; ++i) Hst[i] += DH;
    }
    // final stores (t = TT-1; Hst points at row TT)
    #pragma unroll
    for (int q = 0; q < 8; ++q)
        #pragma unroll
        for (int i = 0; i < 4; ++i)
            Hst[i][-512 + q * 16] = acc[q][i];
}

// ---------------- Pass 3: O = H(65536x512) @ wO(512x128) ----------------
__global__ __launch_bounds__(256, 1) void k_O(const float* __restrict__ H,
                                              const float* __restrict__ wO,
                                              float* __restrict__ O) {
    __shared__ __align__(16) f16 Bt[DOUT][520];  // wO^T [n][k]
    __shared__ __align__(16) f16 At[64][136];    // H tile [m][k-chunk]
    const int tid = threadIdx.x;
    const int wv = tid >> 6, ln = tid & 63, l15 = ln & 15, g = ln >> 4;
    const int m0 = (int)blockIdx.x * 64;

    for (int u = 0; u < 64; ++u) {
        int flat = u * 256 + tid;
        int r = flat >> 5;
        int c4 = (flat & 31) << 2;
        const float4 w4 = *(const float4*)(wO + (size_t)r * DOUT + c4);
        Bt[c4 + 0][r] = (f16)w4.x;
        Bt[c4 + 1][r] = (f16)w4.y;
        Bt[c4 + 2][r] = (f16)w4.z;
        Bt[c4 + 3][r] = (f16)w4.w;
    }

    f32x4 acc[8];
    #pragma unroll
    for (int nt = 0; nt < 8; ++nt) acc[nt] = (f32x4){0.f, 0.f, 0.f, 0.f};

    for (int kc = 0; kc < 4; ++kc) {
        __syncthreads();
        {
            int r = tid >> 2;
            int cb = (tid & 3) << 5;
            #pragma unroll
            for (int u = 0; u < 8; ++u) {
                int c = cb + u * 4;
                const float4 x4 = *(const float4*)(H + (size_t)(m0 + r) * DH + kc * 128 + c);
                f16x4 h4;
                h4[0] = (f16)x4.x; h4[1] = (f16)x4.y; h4[2] = (f16)x4.z; h4[3] = (f16)x4.w;
                *(f16x4*)((char*)&At[r][0] + c * 2) = h4;
            }
        }
        __syncthreads();
        #pragma unroll
        for (int c = 0; c < 8; ++c) {
            const int k0 = c * 16 + g * 4;
            const f16x4 a = *(const f16x4*)((const char*)&At[wv * 16 + l15][0] + k0 * 2);
            #pragma unroll
            for (int nt = 0; nt < 8; ++nt) {
                const f16x4 b =
                    *(const f16x4*)((const char*)&Bt[nt * 16 + l15][0] + (kc * 128 + k0) * 2);
                acc[nt] = MFMA16(a, b, acc[nt]);
            }
        }
    }
    #pragma unroll
    for (int i = 0; i < 4; ++i) {
        const int m = m0 + wv * 16 + g * 4 + i;
        #pragma unroll
        for (int nt = 0; nt < 8; ++nt) O[(size_t)m * DOUT + nt * 16 + l15] = acc[nt][i];
    }
}

extern "C" void kernel_launch(void* const* d_in, const int* in_sizes, int n_in,
                              void* d_out, int out_size, void* d_ws, size_t ws_size,
                              hipStream_t stream) {
    const float* X  = (const float*)d_in[0];
    const float* h0 = (const float*)d_in[1];
    const float* wI = (const float*)d_in[2];
    const float* wR = (const float*)d_in[3];
    const float* wO = (const float*)d_in[4];
    float* O = (float*)d_out;
    float* H = O + O_ELEMS;  // H region; also holds xI (fp32) before in-place scan

    k_xI<<<1024, 256, 0, stream>>>(X, wI, H);   // xI -> H region
    k_scan<<<4, 256, 0, stream>>>(wR, h0, H);   // in-place: xI -> H
    k_O<<<1024, 256, 0, stream>>>(H, wO, O);    // O = H @ wO
}

// Round 3
// 4806.043 us; speedup vs baseline: 3.0876x; 3.0876x over previous
//
#include <hip/hip_runtime.h>
#include <cstdint>
#include <cstddef>

typedef _Float16 f16;
typedef _Float16 f16x4 __attribute__((ext_vector_type(4)));
typedef float f32x4 __attribute__((ext_vector_type(4)));

#define MFMA16(a, b, c) __builtin_amdgcn_mfma_f32_16x16x16f16((a), (b), (c), 0, 0, 0)

constexpr int TT = 1024, DIN = 128, DH = 512, DOUT = 128;
constexpr size_t O_ELEMS = (size_t)64 * 1024 * 128;

// ---------------- Pass 1: xI = X(65536x128) @ wI(128x512) -> H region (fp32) ----------------
__global__ __launch_bounds__(256, 1) void k_xI(const float* __restrict__ X,
                                               const float* __restrict__ wI,
                                               float* __restrict__ xI) {
    __shared__ __align__(16) f16 Bt[DH][136];
    __shared__ __align__(16) f16 At[64][136];
    const int tid = threadIdx.x;
    const int wv = tid >> 6, ln = tid & 63, l15 = ln & 15, g = ln >> 4;
    const int m0 = (int)blockIdx.x * 64;

    for (int u = 0; u < 64; ++u) {
        int flat = u * 256 + tid;
        int r = flat >> 7;
        int c4 = (flat & 127) << 2;
        const float4 w4 = *(const float4*)(wI + (size_t)r * DH + c4);
        Bt[c4 + 0][r] = (f16)w4.x;
        Bt[c4 + 1][r] = (f16)w4.y;
        Bt[c4 + 2][r] = (f16)w4.z;
        Bt[c4 + 3][r] = (f16)w4.w;
    }
    {
        int r = tid >> 2;
        int cb = (tid & 3) << 5;
        #pragma unroll
        for (int u = 0; u < 8; ++u) {
            int c = cb + u * 4;
            const float4 x4 = *(const float4*)(X + (size_t)(m0 + r) * DIN + c);
            f16x4 h4;
            h4[0] = (f16)x4.x; h4[1] = (f16)x4.y; h4[2] = (f16)x4.z; h4[3] = (f16)x4.w;
            *(f16x4*)((char*)&At[r][0] + c * 2) = h4;
        }
    }
    __syncthreads();

    f32x4 acc[4][8];
    #pragma unroll
    for (int mt = 0; mt < 4; ++mt)
        #pragma unroll
        for (int nt = 0; nt < 8; ++nt) acc[mt][nt] = (f32x4){0.f, 0.f, 0.f, 0.f};

    #pragma unroll
    for (int c = 0; c < 8; ++c) {
        const int k0 = c * 16 + g * 4;
        f16x4 a[4];
        #pragma unroll
        for (int mt = 0; mt < 4; ++mt)
            a[mt] = *(const f16x4*)((const char*)&At[mt * 16 + l15][0] + k0 * 2);
        #pragma unroll
        for (int nt = 0; nt < 8; ++nt) {
            const int n = wv * 128 + nt * 16 + l15;
            const f16x4 b = *(const f16x4*)((const char*)&Bt[n][0] + k0 * 2);
            #pragma unroll
            for (int mt = 0; mt < 4; ++mt) acc[mt][nt] = MFMA16(a[mt], b, acc[mt][nt]);
        }
    }
    #pragma unroll
    for (int mt = 0; mt < 4; ++mt) {
        #pragma unroll
        for (int i = 0; i < 4; ++i) {
            const int m = m0 + mt * 16 + g * 4 + i;
            float* orow = xI + (size_t)m * DH + wv * 128 + l15;
            #pragma unroll
            for (int nt = 0; nt < 8; ++nt) orow[nt * 16] = acc[mt][nt][i];
        }
    }
}

// ---------------- Pass 2: recurrent scan -------------------------------------------------
// 4 blocks x 16 batches, 8 waves/block (2 per SIMD, hard 256-VGPR cap).
// Per wave: 64 output columns = 4 j-tiles; 3 in registers (192 VGPR), 1 in LDS.
// LDS map (163840 B exactly):
//   [0,16K)      hb[0] : h state parity 0, [16 r][512 k] f16, XOR-swizzled
//   [16K,32K)    hb[1] : parity 1
//   [32K,160K)   wt[8] : per-wave weight j-tile, [16 j][512 k] f16, XOR-swizzled
// Swizzle: addr = row*1024 + (byteoff ^ (row<<3)). Verified: every b64 operand
// read lands 4 dwords/bank = LDS floor (zero conflict).
__global__ __launch_bounds__(512, 2) void k_scan(const float* __restrict__ wR,
                                                 const float* __restrict__ h0,
                                                 float* __restrict__ Hb) {
    __shared__ __align__(16) char sm[163840];
    const int tid = threadIdx.x;
    const int wv = tid >> 6, ln = tid & 63, l15 = ln & 15, g = ln >> 4;
    const int bb = (int)blockIdx.x * 16;

    // ---- stage wR: 3 register j-tiles per wave (j = wv*64 + q*16 + l15) ----
    f16x4 Brf[3][32];
    #pragma unroll
    for (int q = 0; q < 3; ++q) {
        const int j = wv * 64 + q * 16 + l15;
        #pragma unroll
        for (int c = 0; c < 32; ++c) {
            const int k = c * 16 + g * 4;
            const float* p = wR + (size_t)k * DH + j;
            f16x4 v;
            v[0] = (f16)p[0];
            v[1] = (f16)p[DH];
            v[2] = (f16)p[2 * DH];
            v[3] = (f16)p[3 * DH];
            Brf[q][c] = v;
        }
    }
    // ---- stage wR: 1 LDS j-tile per wave (j = wv*64 + 48 + j16), cooperative ----
    for (int idx = tid; idx < 8 * 16 * 512; idx += 512) {
        const int j16 = idx & 15;
        const int k = (idx >> 4) & 511;
        const int t8 = idx >> 13;
        const float v = wR[(size_t)k * DH + t8 * 64 + 48 + j16];
        *(f16*)(sm + 32768 + t8 * 16384 + j16 * 1024 +
                (((uint32_t)(k * 2)) ^ ((uint32_t)j16 << 3))) = (f16)v;
    }
    // ---- h0 broadcast into hb[0] ----
    {
        const int j = tid;  // 0..511
        const f16 v = (f16)h0[j];
        #pragma unroll
        for (uint32_t r = 0; r < 16; ++r)
            *(f16*)(sm + r * 1024 + (((uint32_t)(j * 2)) ^ (r << 3))) = v;
    }

    const int jbase = wv * 64 + l15;
    float* Hp[4];
    #pragma unroll
    for (int i = 0; i < 4; ++i)
        Hp[i] = Hb + (size_t)(bb + g * 4 + i) * TT * DH + jbase;

    const uint32_t gx = ((uint32_t)(g ^ l15)) << 3;  // (g*8) ^ (l15<<3)
    const uint32_t lanebase = (uint32_t)l15 * 1024;
    const uint32_t jb2 = (uint32_t)jbase * 2;

    // prologue: xI(0) into xr
    float xr[4][4];
    #pragma unroll
    for (int q = 0; q < 4; ++q)
        #pragma unroll
        for (int i = 0; i < 4; ++i) xr[q][i] = Hp[i][q * 16];

    f32x4 acc[4];

    __syncthreads();

    #pragma unroll 1
    for (int t = 0; t < TT; ++t) {
        const uint32_t p = (uint32_t)(t & 1);
        // deferred H stores of step t-1 (Hp points at row t)
        if (t > 0) {
            #pragma unroll
            for (int q = 0; q < 4; ++q)
                #pragma unroll
                for (int i = 0; i < 4; ++i) Hp[i][q * 16 - 512] = acc[q][i];
        }
        // acc <- xI(t)  (MFMA C-in carries the input projection)
        #pragma unroll
        for (int q = 0; q < 4; ++q)
            #pragma unroll
            for (int i = 0; i < 4; ++i) acc[q][i] = xr[q][i];
        // prefetch xI(t+1); lands during the MFMA phase
        if (t + 1 < TT) {
            #pragma unroll
            for (int q = 0; q < 4; ++q)
                #pragma unroll
                for (int i = 0; i < 4; ++i) xr[q][i] = Hp[i][q * 16 + 512];
        }

        // h @ wR : 32 k-chunks, 3 register B-tiles + 1 LDS B-tile
        {
            const char* hbp = sm + p * 16384 + lanebase;
            const char* blp = sm + 32768 + (uint32_t)wv * 16384 + lanebase;
            #pragma unroll
            for (int c = 0; c < 32; ++c) {
                const uint32_t off = ((uint32_t)(c * 32)) ^ gx;
                const f16x4 a = *(const f16x4*)(hbp + off);
                acc[0] = MFMA16(a, Brf[0][c], acc[0]);
                acc[1] = MFMA16(a, Brf[1][c], acc[1]);
                acc[2] = MFMA16(a, Brf[2][c], acc[2]);
                const f16x4 b3 = *(const f16x4*)(blp + off);
                acc[3] = MFMA16(a, b3, acc[3]);
            }
        }

        // epilogue: th = tanh(acc); acc keeps fp32 th; hb[p^1] <- f16 th
        {
            char* hw = sm + (p ^ 1u) * 16384;
            #pragma unroll
            for (int q = 0; q < 4; ++q) {
                #pragma unroll
                for (int i = 0; i < 4; ++i) {
                    const uint32_t r = (uint32_t)g * 4 + (uint32_t)i;
                    const float x = acc[q][i];
                    const float e = __builtin_amdgcn_exp2f(x * 2.8853900817779268f);
                    const float th = 1.0f - 2.0f * __builtin_amdgcn_rcpf(e + 1.0f);
                    acc[q][i] = th;
                    *(f16*)(hw + r * 1024 + ((jb2 + (uint32_t)q * 32) ^ (r << 3))) = (f16)th;
                }
            }
        }
        __syncthreads();  // hb[p^1] complete; also covers prior reads of hb[p^1]

        #pragma unroll
        for (int i = 0; i < 4; ++i) Hp[i] += DH;
    }
    // final stores (Hp points at row TT)
    #pragma unroll
    for (int q = 0; q < 4; ++q)
        #pragma unroll
        for (int i = 0; i < 4; ++i) Hp[i][q * 16 - 512] = acc[q][i];
}

// ---------------- Pass 3: O = H(65536x512) @ wO(512x128) ----------------
__global__ __launch_bounds__(256, 1) void k_O(const float* __restrict__ H,
                                              const float* __restrict__ wO,
                                              float* __restrict__ O) {
    __shared__ __align__(16) f16 Bt[DOUT][520];
    __shared__ __align__(16) f16 At[64][136];
    const int tid = threadIdx.x;
    const int wv = tid >> 6, ln = tid & 63, l15 = ln & 15, g = ln >> 4;
    const int m0 = (int)blockIdx.x * 64;

    for (int u = 0; u < 64; ++u) {
        int flat = u * 256 + tid;
        int r = flat >> 5;
        int c4 = (flat & 31) << 2;
        const float4 w4 = *(const float4*)(wO + (size_t)r * DOUT + c4);
        Bt[c4 + 0][r] = (f16)w4.x;
        Bt[c4 + 1][r] = (f16)w4.y;
        Bt[c4 + 2][r] = (f16)w4.z;
        Bt[c4 + 3][r] = (f16)w4.w;
    }

    f32x4 acc[8];
    #pragma unroll
    for (int nt = 0; nt < 8; ++nt) acc[nt] = (f32x4){0.f, 0.f, 0.f, 0.f};

    for (int kc = 0; kc < 4; ++kc) {
        __syncthreads();
        {
            int r = tid >> 2;
            int cb = (tid & 3) << 5;
            #pragma unroll
            for (int u = 0; u < 8; ++u) {
                int c = cb + u * 4;
                const float4 x4 = *(const float4*)(H + (size_t)(m0 + r) * DH + kc * 128 + c);
                f16x4 h4;
                h4[0] = (f16)x4.x; h4[1] = (f16)x4.y; h4[2] = (f16)x4.z; h4[3] = (f16)x4.w;
                *(f16x4*)((char*)&At[r][0] + c * 2) = h4;
            }
        }
        __syncthreads();
        #pragma unroll
        for (int c = 0; c < 8; ++c) {
            const int k0 = c * 16 + g * 4;
            const f16x4 a = *(const f16x4*)((const char*)&At[wv * 16 + l15][0] + k0 * 2);
            #pragma unroll
            for (int nt = 0; nt < 8; ++nt) {
                const f16x4 b =
                    *(const f16x4*)((const char*)&Bt[nt * 16 + l15][0] + (kc * 128 + k0) * 2);
                acc[nt] = MFMA16(a, b, acc[nt]);
            }
        }
    }
    #pragma unroll
    for (int i = 0; i < 4; ++i) {
        const int m = m0 + wv * 16 + g * 4 + i;
        #pragma unroll
        for (int nt = 0; nt < 8; ++nt) O[(size_t)m * DOUT + nt * 16 + l15] = acc[nt][i];
    }
}

extern "C" void kernel_launch(void* const* d_in, const int* in_sizes, int n_in,
                              void* d_out, int out_size, void* d_ws, size_t ws_size,
                              hipStream_t stream) {
    const float* X  = (const float*)d_in[0];
    const float* h0 = (const float*)d_in[1];
    const float* wI = (const float*)d_in[2];
    const float* wR = (const float*)d_in[3];
    const float* wO = (const float*)d_in[4];
    float* O = (float*)d_out;
    float* H = O + O_ELEMS;  // H region; also holds xI (fp32) before in-place scan

    k_xI<<<1024, 256, 0, stream>>>(X, wI, H);   // xI -> H region
    k_scan<<<4, 512, 0, stream>>>(wR, h0, H);   // in-place: xI -> H
    k_O<<<1024, 256, 0, stream>>>(H, wO, O);    // O = H @ wO
}

// Round 4
// 3848.101 us; speedup vs baseline: 3.8562x; 1.2489x over previous
//
#include <hip/hip_runtime.h>
#include <cstdint>
#include <cstddef>

typedef _Float16 f16;
typedef _Float16 f16x4 __attribute__((ext_vector_type(4)));
typedef _Float16 f16x8 __attribute__((ext_vector_type(8)));
typedef float f32x4 __attribute__((ext_vector_type(4)));

#define MFMA16(a, b, c) __builtin_amdgcn_mfma_f32_16x16x16f16((a), (b), (c), 0, 0, 0)
#define MFMA32(a, b, c) __builtin_amdgcn_mfma_f32_16x16x32_f16((a), (b), (c), 0, 0, 0)

constexpr int TT = 1024, DIN = 128, DH = 512, DOUT = 128;
constexpr size_t O_ELEMS = (size_t)64 * 1024 * 128;

// ---------------- Pass 1: xI = X(65536x128) @ wI(128x512) -> H region (fp32) ----------------
__global__ __launch_bounds__(256, 1) void k_xI(const float* __restrict__ X,
                                               const float* __restrict__ wI,
                                               float* __restrict__ xI) {
    __shared__ __align__(16) f16 Bt[DH][136];
    __shared__ __align__(16) f16 At[64][136];
    const int tid = threadIdx.x;
    const int wv = tid >> 6, ln = tid & 63, l15 = ln & 15, g = ln >> 4;
    const int m0 = (int)blockIdx.x * 64;

    for (int u = 0; u < 64; ++u) {
        int flat = u * 256 + tid;
        int r = flat >> 7;
        int c4 = (flat & 127) << 2;
        const float4 w4 = *(const float4*)(wI + (size_t)r * DH + c4);
        Bt[c4 + 0][r] = (f16)w4.x;
        Bt[c4 + 1][r] = (f16)w4.y;
        Bt[c4 + 2][r] = (f16)w4.z;
        Bt[c4 + 3][r] = (f16)w4.w;
    }
    {
        int r = tid >> 2;
        int cb = (tid & 3) << 5;
        #pragma unroll
        for (int u = 0; u < 8; ++u) {
            int c = cb + u * 4;
            const float4 x4 = *(const float4*)(X + (size_t)(m0 + r) * DIN + c);
            f16x4 h4;
            h4[0] = (f16)x4.x; h4[1] = (f16)x4.y; h4[2] = (f16)x4.z; h4[3] = (f16)x4.w;
            *(f16x4*)((char*)&At[r][0] + c * 2) = h4;
        }
    }
    __syncthreads();

    f32x4 acc[4][8];
    #pragma unroll
    for (int mt = 0; mt < 4; ++mt)
        #pragma unroll
        for (int nt = 0; nt < 8; ++nt) acc[mt][nt] = (f32x4){0.f, 0.f, 0.f, 0.f};

    #pragma unroll
    for (int c = 0; c < 8; ++c) {
        const int k0 = c * 16 + g * 4;
        f16x4 a[4];
        #pragma unroll
        for (int mt = 0; mt < 4; ++mt)
            a[mt] = *(const f16x4*)((const char*)&At[mt * 16 + l15][0] + k0 * 2);
        #pragma unroll
        for (int nt = 0; nt < 8; ++nt) {
            const int n = wv * 128 + nt * 16 + l15;
            const f16x4 b = *(const f16x4*)((const char*)&Bt[n][0] + k0 * 2);
            #pragma unroll
            for (int mt = 0; mt < 4; ++mt) acc[mt][nt] = MFMA16(a[mt], b, acc[mt][nt]);
        }
    }
    #pragma unroll
    for (int mt = 0; mt < 4; ++mt) {
        #pragma unroll
        for (int i = 0; i < 4; ++i) {
            const int m = m0 + mt * 16 + g * 4 + i;
            float* orow = xI + (size_t)m * DH + wv * 128 + l15;
            #pragma unroll
            for (int nt = 0; nt < 8; ++nt) orow[nt * 16] = acc[mt][nt][i];
        }
    }
}

// ---------------- Pass 2: recurrent scan -------------------------------------------------
// 4 blocks x 16 batches, 8 waves/block (2/SIMD). Full-rate x32 MFMA (K=32 chunks).
// Per wave: 64 j = 4 tiles; 3 in registers (f16x8 Brf[3][16] = 192 VGPR), 1 in LDS.
// LDS (163840 B exactly):
//   [0,16K)    hb[0]: h, [16 r][512 k] f16, swizzled  |  [16K,32K) hb[1]
//   [32K,160K) per-wave B j-tile, [16 j][512 k] f16, swizzled
// Swizzle: addr = row*1024 + (byteoff ^ ((row&7)<<4)) -- 16B-aligned, b128 reads
// land 2 lanes/bank (free), zero true conflicts.
__global__ __launch_bounds__(512, 2) void k_scan(const float* __restrict__ wR,
                                                 const float* __restrict__ h0,
                                                 float* __restrict__ Hb) {
    __shared__ __align__(16) char sm[163840];
    const int tid = threadIdx.x;
    const int wv = tid >> 6, ln = tid & 63, l15 = ln & 15, g = ln >> 4;
    const int bb = (int)blockIdx.x * 16;

    // ---- stage wR: 3 register j-tiles per wave; frag[i] = wR[c*32+g*8+i][j] ----
    f16x8 Brf[3][16];
    #pragma unroll
    for (int q = 0; q < 3; ++q) {
        const int j = wv * 64 + q * 16 + l15;
        #pragma unroll
        for (int c = 0; c < 16; ++c) {
            const float* pw = wR + (size_t)(c * 32 + g * 8) * DH + j;
            f16x8 v;
            #pragma unroll
            for (int i = 0; i < 8; ++i) v[i] = (f16)pw[(size_t)i * DH];
            Brf[q][c] = v;
        }
    }
    // ---- stage wR: 1 LDS j-tile per wave (j = t8*64 + 48 + j16), cooperative ----
    for (int idx = tid; idx < 8 * 16 * 512; idx += 512) {
        const int j16 = idx & 15;
        const int k = (idx >> 4) & 511;
        const int t8 = idx >> 13;
        const float v = wR[(size_t)k * DH + t8 * 64 + 48 + j16];
        *(f16*)(sm + 32768 + t8 * 16384 + j16 * 1024 +
                (((uint32_t)(k * 2)) ^ (((uint32_t)(j16 & 7)) << 4))) = (f16)v;
    }
    // ---- h0 broadcast into hb[0] ----
    {
        const int j = tid;  // 0..511
        const f16 v = (f16)h0[j];
        #pragma unroll
        for (uint32_t r = 0; r < 16; ++r)
            *(f16*)(sm + r * 1024 + (((uint32_t)(j * 2)) ^ ((r & 7u) << 4))) = v;
    }

    const int jbase = wv * 64 + l15;
    float* Hp[4];
    #pragma unroll
    for (int i = 0; i < 4; ++i)
        Hp[i] = Hb + (size_t)(bb + g * 4 + i) * TT * DH + jbase;

    // chunk offset: off = (c<<6) ^ pre, pre = ((g ^ (l15&7))<<4)
    const uint32_t pre = ((uint32_t)(g ^ (l15 & 7))) << 4;
    const uint32_t lanebase = (uint32_t)l15 * 1024;
    const uint32_t jb2 = (uint32_t)jbase * 2;

    // prologue: xI(0) into xr
    float xr[4][4];
    #pragma unroll
    for (int q = 0; q < 4; ++q)
        #pragma unroll
        for (int i = 0; i < 4; ++i) xr[q][i] = Hp[i][q * 16];

    f32x4 acc[4];

    __syncthreads();

    #pragma unroll 1
    for (int t = 0; t < TT; ++t) {
        const uint32_t p = (uint32_t)(t & 1);
        // deferred H stores of step t-1 (Hp points at row t)
        if (t > 0) {
            #pragma unroll
            for (int q = 0; q < 4; ++q)
                #pragma unroll
                for (int i = 0; i < 4; ++i) Hp[i][q * 16 - 512] = acc[q][i];
        }
        // acc <- xI(t)  (MFMA C-in carries the input projection)
        #pragma unroll
        for (int q = 0; q < 4; ++q)
            #pragma unroll
            for (int i = 0; i < 4; ++i) acc[q][i] = xr[q][i];
        // prefetch xI(t+1); lands during the MFMA phase
        if (t + 1 < TT) {
            #pragma unroll
            for (int q = 0; q < 4; ++q)
                #pragma unroll
                for (int i = 0; i < 4; ++i) xr[q][i] = Hp[i][q * 16 + 512];
        }

        // h @ wR : 16 K=32 chunks, 3 register B-tiles + 1 LDS B-tile
        {
            const char* hbp = sm + p * 16384 + lanebase;
            const char* blp = sm + 32768 + (uint32_t)wv * 16384 + lanebase;
            #pragma unroll
            for (int c = 0; c < 16; ++c) {
                const uint32_t off = (((uint32_t)c) << 6) ^ pre;
                const f16x8 a = *(const f16x8*)(hbp + off);
                acc[0] = MFMA32(a, Brf[0][c], acc[0]);
                acc[1] = MFMA32(a, Brf[1][c], acc[1]);
                acc[2] = MFMA32(a, Brf[2][c], acc[2]);
                const f16x8 b3 = *(const f16x8*)(blp + off);
                acc[3] = MFMA32(a, b3, acc[3]);
            }
        }

        // epilogue: th = tanh(acc); acc keeps fp32 th; hb[p^1] <- f16 th
        {
            char* hw = sm + (p ^ 1u) * 16384;
            #pragma unroll
            for (int q = 0; q < 4; ++q) {
                #pragma unroll
                for (int i = 0; i < 4; ++i) {
                    const uint32_t r = (uint32_t)g * 4 + (uint32_t)i;
                    const float x = acc[q][i];
                    const float e = __builtin_amdgcn_exp2f(x * 2.8853900817779268f);
                    const float th = 1.0f - 2.0f * __builtin_amdgcn_rcpf(e + 1.0f);
                    acc[q][i] = th;
                    *(f16*)(hw + r * 1024 +
                            ((jb2 + (uint32_t)q * 32) ^ ((r & 7u) << 4))) = (f16)th;
                }
            }
        }
        __syncthreads();  // hb[p^1] complete before next step reads it

        #pragma unroll
        for (int i = 0; i < 4; ++i) Hp[i] += DH;
    }
    // final stores (Hp points at row TT)
    #pragma unroll
    for (int q = 0; q < 4; ++q)
        #pragma unroll
        for (int i = 0; i < 4; ++i) Hp[i][q * 16 - 512] = acc[q][i];
}

// ---------------- Pass 3: O = H(65536x512) @ wO(512x128) ----------------
__global__ __launch_bounds__(256, 1) void k_O(const float* __restrict__ H,
                                              const float* __restrict__ wO,
                                              float* __restrict__ O) {
    __shared__ __align__(16) f16 Bt[DOUT][520];
    __shared__ __align__(16) f16 At[64][136];
    const int tid = threadIdx.x;
    const int wv = tid >> 6, ln = tid & 63, l15 = ln & 15, g = ln >> 4;
    const int m0 = (int)blockIdx.x * 64;

    for (int u = 0; u < 64; ++u) {
        int flat = u * 256 + tid;
        int r = flat >> 5;
        int c4 = (flat & 31) << 2;
        const float4 w4 = *(const float4*)(wO + (size_t)r * DOUT + c4);
        Bt[c4 + 0][r] = (f16)w4.x;
        Bt[c4 + 1][r] = (f16)w4.y;
        Bt[c4 + 2][r] = (f16)w4.z;
        Bt[c4 + 3][r] = (f16)w4.w;
    }

    f32x4 acc[8];
    #pragma unroll
    for (int nt = 0; nt < 8; ++nt) acc[nt] = (f32x4){0.f, 0.f, 0.f, 0.f};

    for (int kc = 0; kc < 4; ++kc) {
        __syncthreads();
        {
            int r = tid >> 2;
            int cb = (tid & 3) << 5;
            #pragma unroll
            for (int u = 0; u < 8; ++u) {
                int c = cb + u * 4;
                const float4 x4 = *(const float4*)(H + (size_t)(m0 + r) * DH + kc * 128 + c);
                f16x4 h4;
                h4[0] = (f16)x4.x; h4[1] = (f16)x4.y; h4[2] = (f16)x4.z; h4[3] = (f16)x4.w;
                *(f16x4*)((char*)&At[r][0] + c * 2) = h4;
            }
        }
        __syncthreads();
        #pragma unroll
        for (int c = 0; c < 8; ++c) {
            const int k0 = c * 16 + g * 4;
            const f16x4 a = *(const f16x4*)((const char*)&At[wv * 16 + l15][0] + k0 * 2);
            #pragma unroll
            for (int nt = 0; nt < 8; ++nt) {
                const f16x4 b =
                    *(const f16x4*)((const char*)&Bt[nt * 16 + l15][0] + (kc * 128 + k0) * 2);
                acc[nt] = MFMA16(a, b, acc[nt]);
            }
        }
    }
    #pragma unroll
    for (int i = 0; i < 4; ++i) {
        const int m = m0 + wv * 16 + g * 4 + i;
        #pragma unroll
        for (int nt = 0; nt < 8; ++nt) O[(size_t)m * DOUT + nt * 16 + l15] = acc[nt][i];
    }
}

extern "C" void kernel_launch(void* const* d_in, const int* in_sizes, int n_in,
                              void* d_out, int out_size, void* d_ws, size_t ws_size,
                              hipStream_t stream) {
    const float* X  = (const float*)d_in[0];
    const float* h0 = (const float*)d_in[1];
    const float* wI = (const float*)d_in[2];
    const float* wR = (const float*)d_in[3];
    const float* wO = (const float*)d_in[4];
    float* O = (float*)d_out;
    float* H = O + O_ELEMS;  // H region; also holds xI (fp32) before in-place scan

    k_xI<<<1024, 256, 0, stream>>>(X, wI, H);   // xI -> H region
    k_scan<<<4, 512, 0, stream>>>(wR, h0, H);   // in-place: xI -> H
    k_O<<<1024, 256, 0, stream>>>(H, wO, O);    // O = H @ wO
}